// Round 6
// baseline (96.907 us; speedup 1.0000x reference)
//
#include <hip/hip_runtime.h>
#include <math.h>

#define NDIR 32
#define NH   256
#define BLK  512    // 8 waves/block
#define NB   4096   // 4x oversubscription: HW backfills uneven CU dispatch
#define PACKB 256   // prep grid (one max-slot per block)
#define UNIT 64     // items per work unit (1 x 64 lanes)
#define SCALE    2048.0f
#define INVSCALE (1.0 / 2048.0)
#define BIAS  128.5f   // 127.5 (ref bias) + 1.0 (ceil folded into trunc)

// ws layout in 4-byte words:
//  [8 .. 104)    : normalized dirs, 32 x 3 floats
//  [128 .. 384)  : per-block max(norm^2) slots (PACKB floats)
//  [512 .. 512+2*K0) : packed f16 vertex table (uint2 per vertex), packed path only
//  [part_off ..)     : P partial int histograms, each 32*256 int32
#define WS_DIRS 8
#define WS_BMAX 128
#define WS_TAB  512

typedef _Float16 half2v __attribute__((ext_vector_type(2)));

__device__ __forceinline__ unsigned rfl_u(unsigned x) { return __builtin_amdgcn_readfirstlane(x); }
__device__ __forceinline__ int      rfl_i(int x)      { return __builtin_amdgcn_readfirstlane(x); }

__device__ __forceinline__ unsigned pack2(float x, float y) {
    union { half2v h; unsigned u; } c;
    c.h = half2v{(_Float16)x, (_Float16)y};   // RNE (v_cvt_f16_f32)
    return c.u;
}
__device__ __forceinline__ half2v upk(unsigned u) {
    union { unsigned u; half2v h; } c; c.u = u; return c.h;
}
__device__ __forceinline__ float hdot(half2v a, half2v b, float acc) {
#if __has_builtin(__builtin_amdgcn_fdot2)
    return __builtin_amdgcn_fdot2(a, b, acc, false);
#else
    return acc + (float)a.x * (float)b.x + (float)a.y * (float)b.y;
#endif
}
// bin = clip(trunc(hs), 0, 255); hs carries BIAS -> single v_med3_f32 + v_cvt_i32_f32
__device__ __forceinline__ int bin_of(float hs) {
#if __has_builtin(__builtin_amdgcn_fmed3f)
    return (int)__builtin_amdgcn_fmed3f(hs, 0.0f, 255.0f);
#else
    return (int)fminf(fmaxf(hs, 0.0f), 255.0f);
#endif
}

// prep: zero partials + normalize dirs + pack f16 table + per-block max slot (no atomics)
template <bool PACKED>
__global__ void __launch_bounds__(512) wect_prep_kernel(
    const float* __restrict__ dirs, const float* __restrict__ vc, int K0,
    int P, int part_off, float* __restrict__ ws)
{
    int tid  = blockIdx.x * blockDim.x + threadIdx.x;
    int nthr = gridDim.x * blockDim.x;
    for (int i = tid; i < P * NDIR * NH; i += nthr)
        ((int*)ws)[part_off + i] = 0;
    if (blockIdx.x == 0 && threadIdx.x >= 64 && threadIdx.x < 64 + NDIR) {
        int d = threadIdx.x - 64;
        float x = dirs[d * 3 + 0], y = dirs[d * 3 + 1], z = dirs[d * 3 + 2];
        float n = fmaxf(sqrtf(x * x + y * y + z * z), 1e-12f);
        ws[WS_DIRS + d * 3 + 0] = x / n;
        ws[WS_DIRS + d * 3 + 1] = y / n;
        ws[WS_DIRS + d * 3 + 2] = z / n;
    }
    float m = 0.0f;
    uint2* tab = (uint2*)(ws + WS_TAB);
    for (int i = tid; i < K0; i += nthr) {
        float x = vc[3 * i + 0], y = vc[3 * i + 1], z = vc[3 * i + 2];
        m = fmaxf(m, x * x + y * y + z * z);
        if (PACKED) tab[i] = make_uint2(pack2(x, y), pack2(z, 0.0f));
    }
    __shared__ float wm[8];
    #pragma unroll
    for (int off = 32; off > 0; off >>= 1)
        m = fmaxf(m, __shfl_down(m, off, 64));
    if ((threadIdx.x & 63) == 0) wm[threadIdx.x >> 6] = m;
    __syncthreads();
    if (threadIdx.x == 0) {
        float r = wm[0];
        #pragma unroll
        for (int i = 1; i < 8; ++i) r = fmaxf(r, wm[i]);
        ws[WS_BMAX + blockIdx.x] = r;
    }
}

// Unified unit space [0, Ntot): [0,N0) vertex, [N0,N01) edge, [N01,Ntot) tri.
// Block b owns the TYPE-STRIPED set {b, b+NB, b+2NB, ...}: every block gets the
// same type mix (+-1 unit) -> identical block cost with NO cost model. Grid is
// 4x residency capacity so the HW queue backfills uneven per-CU block dispatch
// (grid==capacity pinned occupancy at 62% across R0-R5). Within a block, waves
// balance via an LDS steal counter over the local index n.
template <bool PACKED>
__global__ void __launch_bounds__(BLK, 8) wect_hist_kernel(
    const float* __restrict__ vc, const float* __restrict__ vw,
    const int*   __restrict__ ev, const float* __restrict__ ew,
    const int*   __restrict__ tv, const float* __restrict__ tw,
    int K0, int K1, int K2, int N0, int N01, int Ntot,
    int P, int part_off, float* __restrict__ ws)
{
    __shared__ int hist[NDIR * NH];   // 32 KB -> 4 blocks/CU (512 thr) = 32 waves/CU
    __shared__ int nctr;              // within-block work-steal cursor (LDS atomic)
    for (int i = threadIdx.x; i < (NDIR * NH) / 4; i += BLK)
        ((int4*)hist)[i] = make_int4(0, 0, 0, 0);

    const int wave = threadIdx.x >> 6;
    const int lane = threadIdx.x & 63;
    const int b    = blockIdx.x;
    const int nu   = (Ntot - b + NB - 1) / NB;   // units in this block's stripe
    if (threadIdx.x == 0) nctr = 8;              // 8 waves seed n = 0..7

    // reduce per-block max slots (wave-local, no atomics)
    float m = 0.0f;
    for (int i = lane; i < PACKB; i += 64) m = fmaxf(m, ws[WS_BMAX + i]);
    #pragma unroll
    for (int off = 32; off > 0; off >>= 1)
        m = fmaxf(m, __shfl_xor(m, off, 64));
    float maxh = fmaxf(sqrtf(m), 1e-12f);
    float inv  = 127.5f / maxh;

    // all 32 dirs per wave, packed f16 pairs pinned in SGPRs (64 SGPRs)
    unsigned sdxy[NDIR], sdz[NDIR];
    #pragma unroll
    for (int d = 0; d < NDIR; ++d) {
        float dx = ws[WS_DIRS + 3 * d + 0] * inv;
        float dy = ws[WS_DIRS + 3 * d + 1] * inv;
        float dz = ws[WS_DIRS + 3 * d + 2] * inv;
        sdxy[d] = rfl_u(pack2(dx, dy));
        sdz[d]  = rfl_u(pack2(dz, 0.0f));
    }
    __syncthreads();

    const uint2* tab = (const uint2*)(ws + WS_TAB);
    #define LDC(J, CXY, CZ)                                                  \
        do {                                                                 \
            if constexpr (PACKED) {                                          \
                uint2 r = tab[J];                                            \
                CXY = upk(r.x); CZ = upk(r.y);                               \
            } else {                                                         \
                float _x = vc[3 * (J) + 0], _y = vc[3 * (J) + 1], _z = vc[3 * (J) + 2]; \
                CXY = half2v{(_Float16)_x, (_Float16)_y};                    \
                CZ  = half2v{(_Float16)_z, (_Float16)0.0f};                  \
            }                                                                \
        } while (0)

    // steal loop: grab-next is prefetched (LDS atomic, latency hidden under unit)
    int n = wave;
    while (n < nu) {
        int nxt = 0;
        if (lane == 0) nxt = atomicAdd(&nctr, 1);
        const int u = b + n * NB;

        if (u < N0) {
            // ---- vertex unit: sign +1 ----
            int i = u * UNIT + lane;
            int j = (i < K0) ? i : 0;
            half2v xy, z;
            LDC(j, xy, z);
            int w = (i < K0) ? __float2int_rn(vw[j] * SCALE) : 0;
            #pragma unroll
            for (int d = 0; d < NDIR; ++d) {
                half2v dxy = upk(sdxy[d]), dz = upk(sdz[d]);
                float h = hdot(xy, dxy, hdot(z, dz, BIAS));
                atomicAdd(&hist[d * NH + bin_of(h)], w);
            }
        } else if (u < N01) {
            // ---- edge unit: sign -1 ----
            int i = (u - N0) * UNIT + lane;
            int j = (i < K1) ? i : 0;
            int2 e = ((const int2*)ev)[j];
            half2v axy, az, bxy, bz;
            LDC(e.x, axy, az);
            LDC(e.y, bxy, bz);
            int w = (i < K1) ? -__float2int_rn(ew[j] * SCALE) : 0;
            #pragma unroll
            for (int d = 0; d < NDIR; ++d) {
                half2v dxy = upk(sdxy[d]), dz = upk(sdz[d]);
                float h = fmaxf(hdot(axy, dxy, hdot(az, dz, BIAS)),
                                hdot(bxy, dxy, hdot(bz, dz, BIAS)));
                atomicAdd(&hist[d * NH + bin_of(h)], w);
            }
        } else {
            // ---- triangle unit: sign +1 ----
            int i = (u - N01) * UNIT + lane;
            int j = (i < K2) ? i : 0;
            int va = tv[3 * j + 0], vb = tv[3 * j + 1], vcc = tv[3 * j + 2];
            half2v axy, az, bxy, bz, cxy, cz;
            LDC(va,  axy, az);
            LDC(vb,  bxy, bz);
            LDC(vcc, cxy, cz);
            int w = (i < K2) ? __float2int_rn(tw[j] * SCALE) : 0;
            #pragma unroll
            for (int d = 0; d < NDIR; ++d) {
                half2v dxy = upk(sdxy[d]), dz = upk(sdz[d]);
                // nested fmaxf -> v_max3_f32 fuse
                float h = fmaxf(fmaxf(hdot(axy, dxy, hdot(az, dz, BIAS)),
                                      hdot(bxy, dxy, hdot(bz, dz, BIAS))),
                                hdot(cxy, dxy, hdot(cz, dz, BIAS)));
                atomicAdd(&hist[d * NH + bin_of(h)], w);
            }
        }

        n = rfl_i(nxt);   // lane0's grabbed local index, broadcast at unit end
    }
    #undef LDC

    __syncthreads();
    int* part = (int*)ws + part_off + (blockIdx.x & (P - 1)) * (NDIR * NH);
    for (int i = threadIdx.x; i < NDIR * NH; i += BLK) {
        int v = hist[i];
        if (v != 0) atomicAdd(&part[i], v);
    }
}

// one block per dir: sum P partials (int64-exact), inclusive scan over 256 bins, scale to float
__global__ void wect_reduce_kernel(const float* __restrict__ ws, int P, int part_off,
                                   float* __restrict__ out) {
    __shared__ long long s[NH];
    int d = blockIdx.x, h = threadIdx.x;
    const int* part = (const int*)ws + part_off + d * NH + h;
    long long acc = 0;
    #pragma unroll 4
    for (int p = 0; p < P; ++p)
        acc += (long long)part[p * (NDIR * NH)];
    s[h] = acc;
    __syncthreads();
    #pragma unroll
    for (int off = 1; off < NH; off <<= 1) {
        long long v = (h >= off) ? s[h - off] : 0;
        __syncthreads();
        s[h] += v;
        __syncthreads();
    }
    out[d * NH + h] = (float)((double)s[h] * INVSCALE);
}

extern "C" void kernel_launch(void* const* d_in, const int* in_sizes, int n_in,
                              void* d_out, int out_size, void* d_ws, size_t ws_size,
                              hipStream_t stream) {
    const float* dirs = (const float*)d_in[0];
    const float* vc   = (const float*)d_in[1];
    const float* vw   = (const float*)d_in[2];
    const int*   ev   = (const int*)d_in[3];
    const float* ew   = (const float*)d_in[4];
    const int*   tv   = (const int*)d_in[5];
    const float* tw   = (const float*)d_in[6];
    int K0 = in_sizes[2];
    int K1 = in_sizes[4];
    int K2 = in_sizes[6];

    float* ws  = (float*)d_ws;
    float* out = (float*)d_out;

    long long words = (long long)(ws_size / 4);

    // packed path needs table (2*K0 words) + >=8 partials
    int  part_off = WS_TAB + 2 * K0;
    bool packed   = (words - part_off) >= 8LL * NDIR * NH;
    if (!packed) part_off = WS_TAB;

    long long availP = (words - part_off) / (NDIR * NH);
    int P = 1;
    while (P * 2 <= availP && P < 16) P *= 2;   // 16 partials: enough sharding,
                                                // 4x less zero+reduce traffic

    // unified, type-striped unit space (no cost model)
    int N0 = (K0 + UNIT - 1) / UNIT;
    int N1 = (K1 + UNIT - 1) / UNIT;
    int N2 = (K2 + UNIT - 1) / UNIT;
    int N01 = N0 + N1;
    int Ntot = N01 + N2;

    if (packed) {
        wect_prep_kernel<true><<<PACKB, 512, 0, stream>>>(dirs, vc, K0, P, part_off, ws);
        wect_hist_kernel<true><<<NB, BLK, 0, stream>>>(
            vc, vw, ev, ew, tv, tw, K0, K1, K2, N0, N01, Ntot, P, part_off, ws);
    } else {
        wect_prep_kernel<false><<<PACKB, 512, 0, stream>>>(dirs, vc, K0, P, part_off, ws);
        wect_hist_kernel<false><<<NB, BLK, 0, stream>>>(
            vc, vw, ev, ew, tv, tw, K0, K1, K2, N0, N01, Ntot, P, part_off, ws);
    }
    wect_reduce_kernel<<<NDIR, NH, 0, stream>>>(ws, P, part_off, out);
}

// Round 7
// 75.427 us; speedup vs baseline: 1.2848x; 1.2848x over previous
//
#include <hip/hip_runtime.h>
#include <math.h>

#define NDIR 32
#define NH   256
#define BLK  512    // 8 waves/block
#define NB   1024   // 4 blocks/CU resident (LDS-capped); grid == capacity
#define PACKB 256   // prep grid (one max-slot per block)
#define UNIT 64     // items per work unit (1 x 64 lanes)
#define SCALE    2048.0f
#define INVSCALE (1.0 / 2048.0)
#define BIAS  128.5f   // 127.5 (ref bias) + 1.0 (ceil folded into trunc)

// ws layout in 4-byte words:
//  [8 .. 104)    : normalized dirs, 32 x 3 floats
//  [128 .. 384)  : per-block max(norm^2) slots (PACKB floats)
//  [512 .. 512+2*K0) : packed f16 vertex table (uint2 per vertex), packed path only
//  [part_off ..)     : P partial int histograms, each 32*256 int32
#define WS_DIRS 8
#define WS_BMAX 128
#define WS_TAB  512

typedef _Float16 half2v __attribute__((ext_vector_type(2)));

__device__ __forceinline__ int rfl_i(int x) { return __builtin_amdgcn_readfirstlane(x); }

__device__ __forceinline__ unsigned pack2(float x, float y) {
    union { half2v h; unsigned u; } c;
    c.h = half2v{(_Float16)x, (_Float16)y};   // RNE (v_cvt_f16_f32)
    return c.u;
}
__device__ __forceinline__ half2v upk(unsigned u) {
    union { unsigned u; half2v h; } c; c.u = u; return c.h;
}
// bin = clip(trunc(hs), 0, 255); hs carries BIAS -> v_med3_f32 + v_cvt_i32_f32
__device__ __forceinline__ int bin_of(float hs) {
#if __has_builtin(__builtin_amdgcn_fmed3f)
    return (int)__builtin_amdgcn_fmed3f(hs, 0.0f, 255.0f);
#else
    return (int)fminf(fmaxf(hs, 0.0f), 255.0f);
#endif
}

// prep: zero partials + normalize dirs + pack f16 table + per-block max slot (no atomics)
template <bool PACKED>
__global__ void __launch_bounds__(512) wect_prep_kernel(
    const float* __restrict__ dirs, const float* __restrict__ vc, int K0,
    int P, int part_off, float* __restrict__ ws)
{
    int tid  = blockIdx.x * blockDim.x + threadIdx.x;
    int nthr = gridDim.x * blockDim.x;
    for (int i = tid; i < P * NDIR * NH; i += nthr)
        ((int*)ws)[part_off + i] = 0;
    if (blockIdx.x == 0 && threadIdx.x >= 64 && threadIdx.x < 64 + NDIR) {
        int d = threadIdx.x - 64;
        float x = dirs[d * 3 + 0], y = dirs[d * 3 + 1], z = dirs[d * 3 + 2];
        float n = fmaxf(sqrtf(x * x + y * y + z * z), 1e-12f);
        ws[WS_DIRS + d * 3 + 0] = x / n;
        ws[WS_DIRS + d * 3 + 1] = y / n;
        ws[WS_DIRS + d * 3 + 2] = z / n;
    }
    float m = 0.0f;
    uint2* tab = (uint2*)(ws + WS_TAB);
    for (int i = tid; i < K0; i += nthr) {
        float x = vc[3 * i + 0], y = vc[3 * i + 1], z = vc[3 * i + 2];
        m = fmaxf(m, x * x + y * y + z * z);
        if (PACKED) tab[i] = make_uint2(pack2(x, y), pack2(z, 0.0f));
    }
    __shared__ float wm[8];
    #pragma unroll
    for (int off = 32; off > 0; off >>= 1)
        m = fmaxf(m, __shfl_down(m, off, 64));
    if ((threadIdx.x & 63) == 0) wm[threadIdx.x >> 6] = m;
    __syncthreads();
    if (threadIdx.x == 0) {
        float r = wm[0];
        #pragma unroll
        for (int i = 1; i < 8; ++i) r = fmaxf(r, wm[i]);
        ws[WS_BMAX + blockIdx.x] = r;
    }
}

// Unified unit space [0, Ntot): [0,N0) vertex, [N0,N01) edge, [N01,Ntot) tri.
// Block b owns the TYPE-STRIPED set {b, b+NB, ...} (identical block cost, no model);
// waves balance within block via LDS steal counter. Inner loop is PURE F32 FMA:
// coords converted f16->f32 once per item; dirs read per-dir as float4 from LDS
// (broadcast ds_read_b128, conflict-free). This removes the per-dir f16 convert
// bloat of the fdot2-fallback path (measured ~28 slots/item-dir vs ~10 ideal).
template <bool PACKED>
__global__ void __launch_bounds__(BLK, 8) wect_hist_kernel(
    const float* __restrict__ vc, const float* __restrict__ vw,
    const int*   __restrict__ ev, const float* __restrict__ ew,
    const int*   __restrict__ tv, const float* __restrict__ tw,
    int K0, int K1, int K2, int N0, int N01, int Ntot,
    int P, int part_off, float* __restrict__ ws)
{
    __shared__ int hist[NDIR * NH];   // 32 KB -> 4 blocks/CU (512 thr) = 32 waves/CU
    __shared__ float4 sdirs[NDIR];    // scaled f32 dirs, one b128 broadcast per d
    __shared__ int nctr;              // within-block work-steal cursor (LDS atomic)
    for (int i = threadIdx.x; i < (NDIR * NH) / 4; i += BLK)
        ((int4*)hist)[i] = make_int4(0, 0, 0, 0);

    const int wave = threadIdx.x >> 6;
    const int lane = threadIdx.x & 63;
    const int b    = blockIdx.x;
    const int nu   = (Ntot - b + NB - 1) / NB;   // units in this block's stripe
    if (threadIdx.x == 0) nctr = 8;              // 8 waves seed n = 0..7

    // wave 0 only: reduce per-block max slots, build scaled f32 dirs in LDS
    if (wave == 0) {
        float m = 0.0f;
        for (int i = lane; i < PACKB; i += 64) m = fmaxf(m, ws[WS_BMAX + i]);
        #pragma unroll
        for (int off = 32; off > 0; off >>= 1)
            m = fmaxf(m, __shfl_xor(m, off, 64));
        float maxh = fmaxf(sqrtf(m), 1e-12f);
        float inv  = 127.5f / maxh;
        if (lane < NDIR) {
            sdirs[lane] = make_float4(ws[WS_DIRS + 3 * lane + 0] * inv,
                                      ws[WS_DIRS + 3 * lane + 1] * inv,
                                      ws[WS_DIRS + 3 * lane + 2] * inv, 0.0f);
        }
    }
    __syncthreads();

    const uint2* tab = (const uint2*)(ws + WS_TAB);
    // load one vertex's coords as f32 (f16 table: 3 converts, hoisted per item)
    #define LDC3(J, X, Y, Z)                                                  \
        do {                                                                  \
            if constexpr (PACKED) {                                           \
                uint2 r_ = tab[J];                                            \
                half2v p_ = upk(r_.x), q_ = upk(r_.y);                        \
                X = (float)p_.x; Y = (float)p_.y; Z = (float)q_.x;            \
            } else {                                                          \
                X = vc[3 * (J) + 0]; Y = vc[3 * (J) + 1]; Z = vc[3 * (J) + 2];\
            }                                                                 \
        } while (0)

    // steal loop: grab-next is prefetched (LDS atomic, latency hidden under unit)
    int n = wave;
    while (n < nu) {
        int nxt = 0;
        if (lane == 0) nxt = atomicAdd(&nctr, 1);
        const int u = b + n * NB;

        if (u < N0) {
            // ---- vertex unit: sign +1 ----
            int i = u * UNIT + lane;
            int j = (i < K0) ? i : 0;
            float x, y, z;
            LDC3(j, x, y, z);
            int w = (i < K0) ? __float2int_rn(vw[j] * SCALE) : 0;
            #pragma unroll
            for (int d = 0; d < NDIR; ++d) {
                float4 D = sdirs[d];
                float h = fmaf(x, D.x, fmaf(y, D.y, fmaf(z, D.z, BIAS)));
                atomicAdd(&hist[d * NH + bin_of(h)], w);
            }
        } else if (u < N01) {
            // ---- edge unit: sign -1 ----
            int i = (u - N0) * UNIT + lane;
            int j = (i < K1) ? i : 0;
            int2 e = ((const int2*)ev)[j];
            float ax, ay, az, bx, by, bz;
            LDC3(e.x, ax, ay, az);
            LDC3(e.y, bx, by, bz);
            int w = (i < K1) ? -__float2int_rn(ew[j] * SCALE) : 0;
            #pragma unroll
            for (int d = 0; d < NDIR; ++d) {
                float4 D = sdirs[d];
                float ha = fmaf(ax, D.x, fmaf(ay, D.y, fmaf(az, D.z, BIAS)));
                float hb = fmaf(bx, D.x, fmaf(by, D.y, fmaf(bz, D.z, BIAS)));
                float h  = fmaxf(ha, hb);
                atomicAdd(&hist[d * NH + bin_of(h)], w);
            }
        } else {
            // ---- triangle unit: sign +1 ----
            int i = (u - N01) * UNIT + lane;
            int j = (i < K2) ? i : 0;
            int va = tv[3 * j + 0], vb = tv[3 * j + 1], vcc = tv[3 * j + 2];
            float ax, ay, az, bx, by, bz, cx, cy, cz;
            LDC3(va,  ax, ay, az);
            LDC3(vb,  bx, by, bz);
            LDC3(vcc, cx, cy, cz);
            int w = (i < K2) ? __float2int_rn(tw[j] * SCALE) : 0;
            #pragma unroll
            for (int d = 0; d < NDIR; ++d) {
                float4 D = sdirs[d];
                float ha = fmaf(ax, D.x, fmaf(ay, D.y, fmaf(az, D.z, BIAS)));
                float hb = fmaf(bx, D.x, fmaf(by, D.y, fmaf(bz, D.z, BIAS)));
                float hc = fmaf(cx, D.x, fmaf(cy, D.y, fmaf(cz, D.z, BIAS)));
                float h  = fmaxf(fmaxf(ha, hb), hc);   // v_max3_f32 fuse
                atomicAdd(&hist[d * NH + bin_of(h)], w);
            }
        }

        n = rfl_i(nxt);   // lane0's grabbed local index, broadcast at unit end
    }
    #undef LDC3

    __syncthreads();
    int* part = (int*)ws + part_off + (blockIdx.x & (P - 1)) * (NDIR * NH);
    for (int i = threadIdx.x; i < NDIR * NH; i += BLK) {
        int v = hist[i];
        if (v != 0) atomicAdd(&part[i], v);
    }
}

// one block per dir: sum P partials (int64-exact), inclusive scan over 256 bins, scale to float
__global__ void wect_reduce_kernel(const float* __restrict__ ws, int P, int part_off,
                                   float* __restrict__ out) {
    __shared__ long long s[NH];
    int d = blockIdx.x, h = threadIdx.x;
    const int* part = (const int*)ws + part_off + d * NH + h;
    long long acc = 0;
    #pragma unroll 4
    for (int p = 0; p < P; ++p)
        acc += (long long)part[p * (NDIR * NH)];
    s[h] = acc;
    __syncthreads();
    #pragma unroll
    for (int off = 1; off < NH; off <<= 1) {
        long long v = (h >= off) ? s[h - off] : 0;
        __syncthreads();
        s[h] += v;
        __syncthreads();
    }
    out[d * NH + h] = (float)((double)s[h] * INVSCALE);
}

extern "C" void kernel_launch(void* const* d_in, const int* in_sizes, int n_in,
                              void* d_out, int out_size, void* d_ws, size_t ws_size,
                              hipStream_t stream) {
    const float* dirs = (const float*)d_in[0];
    const float* vc   = (const float*)d_in[1];
    const float* vw   = (const float*)d_in[2];
    const int*   ev   = (const int*)d_in[3];
    const float* ew   = (const float*)d_in[4];
    const int*   tv   = (const int*)d_in[5];
    const float* tw   = (const float*)d_in[6];
    int K0 = in_sizes[2];
    int K1 = in_sizes[4];
    int K2 = in_sizes[6];

    float* ws  = (float*)d_ws;
    float* out = (float*)d_out;

    long long words = (long long)(ws_size / 4);

    // packed path needs table (2*K0 words) + >=8 partials
    int  part_off = WS_TAB + 2 * K0;
    bool packed   = (words - part_off) >= 8LL * NDIR * NH;
    if (!packed) part_off = WS_TAB;

    long long availP = (words - part_off) / (NDIR * NH);
    int P = 1;
    while (P * 2 <= availP && P < 16) P *= 2;   // 16 partials: enough sharding,
                                                // 4x less zero+reduce traffic

    // unified, type-striped unit space (no cost model)
    int N0 = (K0 + UNIT - 1) / UNIT;
    int N1 = (K1 + UNIT - 1) / UNIT;
    int N2 = (K2 + UNIT - 1) / UNIT;
    int N01 = N0 + N1;
    int Ntot = N01 + N2;

    if (packed) {
        wect_prep_kernel<true><<<PACKB, 512, 0, stream>>>(dirs, vc, K0, P, part_off, ws);
        wect_hist_kernel<true><<<NB, BLK, 0, stream>>>(
            vc, vw, ev, ew, tv, tw, K0, K1, K2, N0, N01, Ntot, P, part_off, ws);
    } else {
        wect_prep_kernel<false><<<PACKB, 512, 0, stream>>>(dirs, vc, K0, P, part_off, ws);
        wect_hist_kernel<false><<<NB, BLK, 0, stream>>>(
            vc, vw, ev, ew, tv, tw, K0, K1, K2, N0, N01, Ntot, P, part_off, ws);
    }
    wect_reduce_kernel<<<NDIR, NH, 0, stream>>>(ws, P, part_off, out);
}

// Round 8
// 61.750 us; speedup vs baseline: 1.5693x; 1.2215x over previous
//
#include <hip/hip_runtime.h>
#include <math.h>

#define NDIR 32
#define NH   256
#define BLK  512    // 8 waves/block
#define NB   1024   // 4 blocks/CU resident (LDS-capped); grid == capacity
#define PACKB 256   // prep grid (one max-slot per block)
#define UNIT 64     // items per work unit (1 x 64 lanes)
#define SCALE    2048.0f
#define INVSCALE (1.0 / 2048.0)
#define BIAS  128.5f   // 127.5 (ref bias) + 1.0 (ceil folded into trunc)

// ws layout in 4-byte words:
//  [8 .. 104)    : normalized dirs, 32 x 3 floats
//  [128 .. 384)  : per-block max(norm^2) slots (PACKB floats)
//  [512 .. 512+2*K0) : packed f16 vertex table (uint2 per vertex), packed path only
//  [part_off ..)     : P partial int histograms, each 32*256 int32
#define WS_DIRS 8
#define WS_BMAX 128
#define WS_TAB  512

typedef _Float16 half2v __attribute__((ext_vector_type(2)));

__device__ __forceinline__ unsigned rfl_u(unsigned x) { return __builtin_amdgcn_readfirstlane(x); }
__device__ __forceinline__ int      rfl_i(int x)      { return __builtin_amdgcn_readfirstlane(x); }

__device__ __forceinline__ unsigned pack2(float x, float y) {
    union { half2v h; unsigned u; } c;
    c.h = half2v{(_Float16)x, (_Float16)y};   // RNE (v_cvt_f16_f32)
    return c.u;
}
__device__ __forceinline__ half2v upk(unsigned u) {
    union { unsigned u; half2v h; } c; c.u = u; return c.h;
}
__device__ __forceinline__ float hdot(half2v a, half2v b, float acc) {
#if __has_builtin(__builtin_amdgcn_fdot2)
    return __builtin_amdgcn_fdot2(a, b, acc, false);
#else
    return acc + (float)a.x * (float)b.x + (float)a.y * (float)b.y;
#endif
}
// bin = clip(trunc(hs), 0, 255); hs carries BIAS -> v_med3_f32 + v_cvt_i32_f32
__device__ __forceinline__ int bin_of(float hs) {
#if __has_builtin(__builtin_amdgcn_fmed3f)
    return (int)__builtin_amdgcn_fmed3f(hs, 0.0f, 255.0f);
#else
    return (int)fminf(fmaxf(hs, 0.0f), 255.0f);
#endif
}

// prep: zero partials + normalize dirs + pack f16 table + per-block max slot (no atomics)
template <bool PACKED>
__global__ void __launch_bounds__(512) wect_prep_kernel(
    const float* __restrict__ dirs, const float* __restrict__ vc, int K0,
    int P, int part_off, float* __restrict__ ws)
{
    int tid  = blockIdx.x * blockDim.x + threadIdx.x;
    int nthr = gridDim.x * blockDim.x;
    for (int i = tid; i < P * NDIR * NH; i += nthr)
        ((int*)ws)[part_off + i] = 0;
    if (blockIdx.x == 0 && threadIdx.x >= 64 && threadIdx.x < 64 + NDIR) {
        int d = threadIdx.x - 64;
        float x = dirs[d * 3 + 0], y = dirs[d * 3 + 1], z = dirs[d * 3 + 2];
        float n = fmaxf(sqrtf(x * x + y * y + z * z), 1e-12f);
        ws[WS_DIRS + d * 3 + 0] = x / n;
        ws[WS_DIRS + d * 3 + 1] = y / n;
        ws[WS_DIRS + d * 3 + 2] = z / n;
    }
    float m = 0.0f;
    uint2* tab = (uint2*)(ws + WS_TAB);
    for (int i = tid; i < K0; i += nthr) {
        float x = vc[3 * i + 0], y = vc[3 * i + 1], z = vc[3 * i + 2];
        m = fmaxf(m, x * x + y * y + z * z);
        if (PACKED) tab[i] = make_uint2(pack2(x, y), pack2(z, 0.0f));
    }
    __shared__ float wm[8];
    #pragma unroll
    for (int off = 32; off > 0; off >>= 1)
        m = fmaxf(m, __shfl_down(m, off, 64));
    if ((threadIdx.x & 63) == 0) wm[threadIdx.x >> 6] = m;
    __syncthreads();
    if (threadIdx.x == 0) {
        float r = wm[0];
        #pragma unroll
        for (int i = 1; i < 8; ++i) r = fmaxf(r, wm[i]);
        ws[WS_BMAX + blockIdx.x] = r;
    }
}

// Unified unit space [0, Ntot): [0,N0) vertex, [N0,N01) edge, [N01,Ntot) tri.
// Block b owns the TYPE-STRIPED set {b, b+NB, b+2NB, ...}: every block gets the
// same type mix (+-1 unit) -> identical block cost with NO cost model. Within a
// block, waves balance via an LDS steal counter over the local index n. Dirs are
// SGPR-resident packed f16 (NO per-dir LDS reads: the DS pipe and its in-order
// lgkmcnt queue must stay dedicated to the histogram atomics -- R7 lesson).
template <bool PACKED>
__global__ void __launch_bounds__(BLK, 8) wect_hist_kernel(
    const float* __restrict__ vc, const float* __restrict__ vw,
    const int*   __restrict__ ev, const float* __restrict__ ew,
    const int*   __restrict__ tv, const float* __restrict__ tw,
    int K0, int K1, int K2, int N0, int N01, int Ntot,
    int P, int part_off, float* __restrict__ ws)
{
    __shared__ int hist[NDIR * NH];   // 32 KB -> 4 blocks/CU (512 thr) = 32 waves/CU
    __shared__ int nctr;              // within-block work-steal cursor (LDS atomic)
    for (int i = threadIdx.x; i < (NDIR * NH) / 4; i += BLK)
        ((int4*)hist)[i] = make_int4(0, 0, 0, 0);

    const int wave = threadIdx.x >> 6;
    const int lane = threadIdx.x & 63;
    const int b    = blockIdx.x;
    const int nu   = (Ntot - b + NB - 1) / NB;   // units in this block's stripe
    if (threadIdx.x == 0) nctr = 8;              // 8 waves seed n = 0..7

    // reduce per-block max slots (wave-local, no atomics)
    float m = 0.0f;
    for (int i = lane; i < PACKB; i += 64) m = fmaxf(m, ws[WS_BMAX + i]);
    #pragma unroll
    for (int off = 32; off > 0; off >>= 1)
        m = fmaxf(m, __shfl_xor(m, off, 64));
    float maxh = fmaxf(sqrtf(m), 1e-12f);
    float inv  = 127.5f / maxh;

    // all 32 dirs per wave, packed f16 pairs pinned in SGPRs (64 SGPRs)
    unsigned sdxy[NDIR], sdz[NDIR];
    #pragma unroll
    for (int d = 0; d < NDIR; ++d) {
        float dx = ws[WS_DIRS + 3 * d + 0] * inv;
        float dy = ws[WS_DIRS + 3 * d + 1] * inv;
        float dz = ws[WS_DIRS + 3 * d + 2] * inv;
        sdxy[d] = rfl_u(pack2(dx, dy));
        sdz[d]  = rfl_u(pack2(dz, 0.0f));
    }
    __syncthreads();

    const uint2* tab = (const uint2*)(ws + WS_TAB);
    #define LDC(J, CXY, CZ)                                                  \
        do {                                                                 \
            if constexpr (PACKED) {                                          \
                uint2 r = tab[J];                                            \
                CXY = upk(r.x); CZ = upk(r.y);                               \
            } else {                                                         \
                float _x = vc[3 * (J) + 0], _y = vc[3 * (J) + 1], _z = vc[3 * (J) + 2]; \
                CXY = half2v{(_Float16)_x, (_Float16)_y};                    \
                CZ  = half2v{(_Float16)_z, (_Float16)0.0f};                  \
            }                                                                \
        } while (0)

    // steal loop: grab-next is prefetched (LDS atomic, latency hidden under unit)
    int n = wave;
    while (n < nu) {
        int nxt = 0;
        if (lane == 0) nxt = atomicAdd(&nctr, 1);
        const int u = b + n * NB;

        if (u < N0) {
            // ---- vertex unit: sign +1 ----
            int i = u * UNIT + lane;
            int j = (i < K0) ? i : 0;
            half2v xy, z;
            LDC(j, xy, z);
            int w = (i < K0) ? __float2int_rn(vw[j] * SCALE) : 0;
            #pragma unroll
            for (int d = 0; d < NDIR; ++d) {
                half2v dxy = upk(sdxy[d]), dz = upk(sdz[d]);
                float h = hdot(xy, dxy, hdot(z, dz, BIAS));
                atomicAdd(&hist[d * NH + bin_of(h)], w);
            }
        } else if (u < N01) {
            // ---- edge unit: sign -1 ----
            int i = (u - N0) * UNIT + lane;
            int j = (i < K1) ? i : 0;
            int2 e = ((const int2*)ev)[j];
            half2v axy, az, bxy, bz;
            LDC(e.x, axy, az);
            LDC(e.y, bxy, bz);
            int w = (i < K1) ? -__float2int_rn(ew[j] * SCALE) : 0;
            #pragma unroll
            for (int d = 0; d < NDIR; ++d) {
                half2v dxy = upk(sdxy[d]), dz = upk(sdz[d]);
                float h = fmaxf(hdot(axy, dxy, hdot(az, dz, BIAS)),
                                hdot(bxy, dxy, hdot(bz, dz, BIAS)));
                atomicAdd(&hist[d * NH + bin_of(h)], w);
            }
        } else {
            // ---- triangle unit: sign +1 ----
            int i = (u - N01) * UNIT + lane;
            int j = (i < K2) ? i : 0;
            int va = tv[3 * j + 0], vb = tv[3 * j + 1], vcc = tv[3 * j + 2];
            half2v axy, az, bxy, bz, cxy, cz;
            LDC(va,  axy, az);
            LDC(vb,  bxy, bz);
            LDC(vcc, cxy, cz);
            int w = (i < K2) ? __float2int_rn(tw[j] * SCALE) : 0;
            #pragma unroll
            for (int d = 0; d < NDIR; ++d) {
                half2v dxy = upk(sdxy[d]), dz = upk(sdz[d]);
                // nested fmaxf -> v_max3_f32 fuse
                float h = fmaxf(fmaxf(hdot(axy, dxy, hdot(az, dz, BIAS)),
                                      hdot(bxy, dxy, hdot(bz, dz, BIAS))),
                                hdot(cxy, dxy, hdot(cz, dz, BIAS)));
                atomicAdd(&hist[d * NH + bin_of(h)], w);
            }
        }

        n = rfl_i(nxt);   // lane0's grabbed local index, broadcast at unit end
    }
    #undef LDC

    __syncthreads();
    int* part = (int*)ws + part_off + (blockIdx.x & (P - 1)) * (NDIR * NH);
    for (int i = threadIdx.x; i < NDIR * NH; i += BLK) {
        int v = hist[i];
        if (v != 0) atomicAdd(&part[i], v);
    }
}

// one block per dir: sum P partials (int64-exact), inclusive scan over 256 bins, scale to float
__global__ void wect_reduce_kernel(const float* __restrict__ ws, int P, int part_off,
                                   float* __restrict__ out) {
    __shared__ long long s[NH];
    int d = blockIdx.x, h = threadIdx.x;
    const int* part = (const int*)ws + part_off + d * NH + h;
    long long acc = 0;
    #pragma unroll 4
    for (int p = 0; p < P; ++p)
        acc += (long long)part[p * (NDIR * NH)];
    s[h] = acc;
    __syncthreads();
    #pragma unroll
    for (int off = 1; off < NH; off <<= 1) {
        long long v = (h >= off) ? s[h - off] : 0;
        __syncthreads();
        s[h] += v;
        __syncthreads();
    }
    out[d * NH + h] = (float)((double)s[h] * INVSCALE);
}

extern "C" void kernel_launch(void* const* d_in, const int* in_sizes, int n_in,
                              void* d_out, int out_size, void* d_ws, size_t ws_size,
                              hipStream_t stream) {
    const float* dirs = (const float*)d_in[0];
    const float* vc   = (const float*)d_in[1];
    const float* vw   = (const float*)d_in[2];
    const int*   ev   = (const int*)d_in[3];
    const float* ew   = (const float*)d_in[4];
    const int*   tv   = (const int*)d_in[5];
    const float* tw   = (const float*)d_in[6];
    int K0 = in_sizes[2];
    int K1 = in_sizes[4];
    int K2 = in_sizes[6];

    float* ws  = (float*)d_ws;
    float* out = (float*)d_out;

    long long words = (long long)(ws_size / 4);

    // packed path needs table (2*K0 words) + >=8 partials
    int  part_off = WS_TAB + 2 * K0;
    bool packed   = (words - part_off) >= 8LL * NDIR * NH;
    if (!packed) part_off = WS_TAB;

    long long availP = (words - part_off) / (NDIR * NH);
    int P = 1;
    while (P * 2 <= availP && P < 16) P *= 2;   // 16 partials: enough sharding,
                                                // 4x less zero+reduce traffic

    // unified, type-striped unit space (no cost model)
    int N0 = (K0 + UNIT - 1) / UNIT;
    int N1 = (K1 + UNIT - 1) / UNIT;
    int N2 = (K2 + UNIT - 1) / UNIT;
    int N01 = N0 + N1;
    int Ntot = N01 + N2;

    if (packed) {
        wect_prep_kernel<true><<<PACKB, 512, 0, stream>>>(dirs, vc, K0, P, part_off, ws);
        wect_hist_kernel<true><<<NB, BLK, 0, stream>>>(
            vc, vw, ev, ew, tv, tw, K0, K1, K2, N0, N01, Ntot, P, part_off, ws);
    } else {
        wect_prep_kernel<false><<<PACKB, 512, 0, stream>>>(dirs, vc, K0, P, part_off, ws);
        wect_hist_kernel<false><<<NB, BLK, 0, stream>>>(
            vc, vw, ev, ew, tv, tw, K0, K1, K2, N0, N01, Ntot, P, part_off, ws);
    }
    wect_reduce_kernel<<<NDIR, NH, 0, stream>>>(ws, P, part_off, out);
}

// Round 11
// 61.296 us; speedup vs baseline: 1.5810x; 1.0074x over previous
//
#include <hip/hip_runtime.h>
#include <math.h>

#define NDIR 32
#define NH   256
#define BLK  512    // 8 waves/block
#define NB   1024   // 4 blocks/CU resident (LDS-capped); grid == capacity
#define PACKB 256   // prep grid (one max-slot per block)
#define UNIT 64     // items per work unit (1 x 64 lanes)
#define SCALE    2048.0f
#define INVSCALE (1.0 / 2048.0)
#define BIAS  128.5f   // 127.5 (ref bias) + 1.0 (ceil folded into trunc)

// ws layout in 4-byte words:
//  [8 .. 104)    : normalized dirs, 32 x 3 floats
//  [128 .. 384)  : per-block max(norm^2) slots (PACKB floats)
//  [512 .. 512+2*K0) : packed f16 vertex table (uint2 per vertex), packed path only
//  [part_off ..)     : P partial int histograms, each 32*256 int32
#define WS_DIRS 8
#define WS_BMAX 128
#define WS_TAB  512

typedef _Float16 half2v __attribute__((ext_vector_type(2)));

__device__ __forceinline__ unsigned rfl_u(unsigned x) { return __builtin_amdgcn_readfirstlane(x); }
__device__ __forceinline__ int      rfl_i(int x)      { return __builtin_amdgcn_readfirstlane(x); }

__device__ __forceinline__ unsigned pack2(float x, float y) {
    union { half2v h; unsigned u; } c;
    c.h = half2v{(_Float16)x, (_Float16)y};   // RNE (v_cvt_f16_f32)
    return c.u;
}
__device__ __forceinline__ half2v upk(unsigned u) {
    union { unsigned u; half2v h; } c; c.u = u; return c.h;
}
__device__ __forceinline__ float hdot(half2v a, half2v b, float acc) {
#if __has_builtin(__builtin_amdgcn_fdot2)
    return __builtin_amdgcn_fdot2(a, b, acc, false);
#else
    return acc + (float)a.x * (float)b.x + (float)a.y * (float)b.y;
#endif
}
// bin = clip(trunc(hs), 0, 255); hs carries BIAS -> v_med3_f32 + v_cvt_i32_f32
__device__ __forceinline__ int bin_of(float hs) {
#if __has_builtin(__builtin_amdgcn_fmed3f)
    return (int)__builtin_amdgcn_fmed3f(hs, 0.0f, 255.0f);
#else
    return (int)fminf(fmaxf(hs, 0.0f), 255.0f);
#endif
}

// prep: zero partials + normalize dirs + pack f16 table + per-block max slot (no atomics)
template <bool PACKED>
__global__ void __launch_bounds__(512) wect_prep_kernel(
    const float* __restrict__ dirs, const float* __restrict__ vc, int K0,
    int P, int part_off, float* __restrict__ ws)
{
    int tid  = blockIdx.x * blockDim.x + threadIdx.x;
    int nthr = gridDim.x * blockDim.x;
    for (int i = tid; i < P * NDIR * NH; i += nthr)
        ((int*)ws)[part_off + i] = 0;
    if (blockIdx.x == 0 && threadIdx.x >= 64 && threadIdx.x < 64 + NDIR) {
        int d = threadIdx.x - 64;
        float x = dirs[d * 3 + 0], y = dirs[d * 3 + 1], z = dirs[d * 3 + 2];
        float n = fmaxf(sqrtf(x * x + y * y + z * z), 1e-12f);
        ws[WS_DIRS + d * 3 + 0] = x / n;
        ws[WS_DIRS + d * 3 + 1] = y / n;
        ws[WS_DIRS + d * 3 + 2] = z / n;
    }
    float m = 0.0f;
    uint2* tab = (uint2*)(ws + WS_TAB);
    for (int i = tid; i < K0; i += nthr) {
        float x = vc[3 * i + 0], y = vc[3 * i + 1], z = vc[3 * i + 2];
        m = fmaxf(m, x * x + y * y + z * z);
        if (PACKED) tab[i] = make_uint2(pack2(x, y), pack2(z, 0.0f));
    }
    __shared__ float wm[8];
    #pragma unroll
    for (int off = 32; off > 0; off >>= 1)
        m = fmaxf(m, __shfl_down(m, off, 64));
    if ((threadIdx.x & 63) == 0) wm[threadIdx.x >> 6] = m;
    __syncthreads();
    if (threadIdx.x == 0) {
        float r = wm[0];
        #pragma unroll
        for (int i = 1; i < 8; ++i) r = fmaxf(r, wm[i]);
        ws[WS_BMAX + blockIdx.x] = r;
    }
}

// Unified unit space [0, Ntot): [0,N0) vertex, [N0,N01) edge, [N01,Ntot) tri.
// Block b owns the TYPE-STRIPED set {b, b+NB, b+2NB, ...}: every block gets the
// same type mix (+-1 unit) -> identical block cost with NO cost model. Within a
// block, waves balance via an LDS steal counter over the local index n. Dirs are
// SGPR-resident packed f16 (NO per-dir LDS reads: the DS pipe and its in-order
// lgkmcnt queue must stay dedicated to the histogram atomics -- R7 lesson).
// NOTE (R9/R10 lesson): do NOT replace hdot with per-dir f16->f32 extract+cvt
// feeding f32 FMA -- two independent implementations of that construct produced
// catastrophically wrong histograms (suspected codegen issue under unroll).
template <bool PACKED>
__global__ void __launch_bounds__(BLK, 8) wect_hist_kernel(
    const float* __restrict__ vc, const float* __restrict__ vw,
    const int*   __restrict__ ev, const float* __restrict__ ew,
    const int*   __restrict__ tv, const float* __restrict__ tw,
    int K0, int K1, int K2, int N0, int N01, int Ntot,
    int P, int part_off, float* __restrict__ ws)
{
    __shared__ int hist[NDIR * NH];   // 32 KB -> 4 blocks/CU (512 thr) = 32 waves/CU
    __shared__ int nctr;              // within-block work-steal cursor (LDS atomic)
    for (int i = threadIdx.x; i < (NDIR * NH) / 4; i += BLK)
        ((int4*)hist)[i] = make_int4(0, 0, 0, 0);

    const int wave = threadIdx.x >> 6;
    const int lane = threadIdx.x & 63;
    const int b    = blockIdx.x;
    const int nu   = (Ntot - b + NB - 1) / NB;   // units in this block's stripe
    if (threadIdx.x == 0) nctr = 8;              // 8 waves seed n = 0..7

    // reduce per-block max slots (wave-local, no atomics)
    float m = 0.0f;
    for (int i = lane; i < PACKB; i += 64) m = fmaxf(m, ws[WS_BMAX + i]);
    #pragma unroll
    for (int off = 32; off > 0; off >>= 1)
        m = fmaxf(m, __shfl_xor(m, off, 64));
    float maxh = fmaxf(sqrtf(m), 1e-12f);
    float inv  = 127.5f / maxh;

    // all 32 dirs per wave, packed f16 pairs pinned in SGPRs (64 SGPRs)
    unsigned sdxy[NDIR], sdz[NDIR];
    #pragma unroll
    for (int d = 0; d < NDIR; ++d) {
        float dx = ws[WS_DIRS + 3 * d + 0] * inv;
        float dy = ws[WS_DIRS + 3 * d + 1] * inv;
        float dz = ws[WS_DIRS + 3 * d + 2] * inv;
        sdxy[d] = rfl_u(pack2(dx, dy));
        sdz[d]  = rfl_u(pack2(dz, 0.0f));
    }
    __syncthreads();

    const uint2* tab = (const uint2*)(ws + WS_TAB);
    #define LDC(J, CXY, CZ)                                                  \
        do {                                                                 \
            if constexpr (PACKED) {                                          \
                uint2 r = tab[J];                                            \
                CXY = upk(r.x); CZ = upk(r.y);                               \
            } else {                                                         \
                float _x = vc[3 * (J) + 0], _y = vc[3 * (J) + 1], _z = vc[3 * (J) + 2]; \
                CXY = half2v{(_Float16)_x, (_Float16)_y};                    \
                CZ  = half2v{(_Float16)_z, (_Float16)0.0f};                  \
            }                                                                \
        } while (0)

    // steal loop: grab-next is prefetched (LDS atomic, latency hidden under unit)
    int n = wave;
    while (n < nu) {
        int nxt = 0;
        if (lane == 0) nxt = atomicAdd(&nctr, 1);
        const int u = b + n * NB;

        if (u < N0) {
            // ---- vertex unit: sign +1 ----
            int i = u * UNIT + lane;
            int j = (i < K0) ? i : 0;
            half2v xy, z;
            LDC(j, xy, z);
            int w = (i < K0) ? __float2int_rn(vw[j] * SCALE) : 0;
            #pragma unroll
            for (int d = 0; d < NDIR; ++d) {
                half2v dxy = upk(sdxy[d]), dz = upk(sdz[d]);
                float h = hdot(xy, dxy, hdot(z, dz, BIAS));
                atomicAdd(&hist[d * NH + bin_of(h)], w);
            }
        } else if (u < N01) {
            // ---- edge unit: sign -1 ----
            int i = (u - N0) * UNIT + lane;
            int j = (i < K1) ? i : 0;
            int2 e = ((const int2*)ev)[j];
            half2v axy, az, bxy, bz;
            LDC(e.x, axy, az);
            LDC(e.y, bxy, bz);
            int w = (i < K1) ? -__float2int_rn(ew[j] * SCALE) : 0;
            #pragma unroll
            for (int d = 0; d < NDIR; ++d) {
                half2v dxy = upk(sdxy[d]), dz = upk(sdz[d]);
                float h = fmaxf(hdot(axy, dxy, hdot(az, dz, BIAS)),
                                hdot(bxy, dxy, hdot(bz, dz, BIAS)));
                atomicAdd(&hist[d * NH + bin_of(h)], w);
            }
        } else {
            // ---- triangle unit: sign +1 ----
            int i = (u - N01) * UNIT + lane;
            int j = (i < K2) ? i : 0;
            int va = tv[3 * j + 0], vb = tv[3 * j + 1], vcc = tv[3 * j + 2];
            half2v axy, az, bxy, bz, cxy, cz;
            LDC(va,  axy, az);
            LDC(vb,  bxy, bz);
            LDC(vcc, cxy, cz);
            int w = (i < K2) ? __float2int_rn(tw[j] * SCALE) : 0;
            #pragma unroll
            for (int d = 0; d < NDIR; ++d) {
                half2v dxy = upk(sdxy[d]), dz = upk(sdz[d]);
                // nested fmaxf -> v_max3_f32 fuse
                float h = fmaxf(fmaxf(hdot(axy, dxy, hdot(az, dz, BIAS)),
                                      hdot(bxy, dxy, hdot(bz, dz, BIAS))),
                                hdot(cxy, dxy, hdot(cz, dz, BIAS)));
                atomicAdd(&hist[d * NH + bin_of(h)], w);
            }
        }

        n = rfl_i(nxt);   // lane0's grabbed local index, broadcast at unit end
    }
    #undef LDC

    __syncthreads();
    int* part = (int*)ws + part_off + (blockIdx.x & (P - 1)) * (NDIR * NH);
    for (int i = threadIdx.x; i < NDIR * NH; i += BLK) {
        int v = hist[i];
        if (v != 0) atomicAdd(&part[i], v);
    }
}

// one block per dir: sum P partials (int64-exact), inclusive scan over 256 bins, scale to float
__global__ void wect_reduce_kernel(const float* __restrict__ ws, int P, int part_off,
                                   float* __restrict__ out) {
    __shared__ long long s[NH];
    int d = blockIdx.x, h = threadIdx.x;
    const int* part = (const int*)ws + part_off + d * NH + h;
    long long acc = 0;
    #pragma unroll 4
    for (int p = 0; p < P; ++p)
        acc += (long long)part[p * (NDIR * NH)];
    s[h] = acc;
    __syncthreads();
    #pragma unroll
    for (int off = 1; off < NH; off <<= 1) {
        long long v = (h >= off) ? s[h - off] : 0;
        __syncthreads();
        s[h] += v;
        __syncthreads();
    }
    out[d * NH + h] = (float)((double)s[h] * INVSCALE);
}

extern "C" void kernel_launch(void* const* d_in, const int* in_sizes, int n_in,
                              void* d_out, int out_size, void* d_ws, size_t ws_size,
                              hipStream_t stream) {
    const float* dirs = (const float*)d_in[0];
    const float* vc   = (const float*)d_in[1];
    const float* vw   = (const float*)d_in[2];
    const int*   ev   = (const int*)d_in[3];
    const float* ew   = (const float*)d_in[4];
    const int*   tv   = (const int*)d_in[5];
    const float* tw   = (const float*)d_in[6];
    int K0 = in_sizes[2];
    int K1 = in_sizes[4];
    int K2 = in_sizes[6];

    float* ws  = (float*)d_ws;
    float* out = (float*)d_out;

    long long words = (long long)(ws_size / 4);

    // packed path needs table (2*K0 words) + >=8 partials
    int  part_off = WS_TAB + 2 * K0;
    bool packed   = (words - part_off) >= 8LL * NDIR * NH;
    if (!packed) part_off = WS_TAB;

    long long availP = (words - part_off) / (NDIR * NH);
    int P = 1;
    while (P * 2 <= availP && P < 16) P *= 2;   // 16 partials: enough sharding,
                                                // 4x less zero+reduce traffic

    // unified, type-striped unit space (no cost model)
    int N0 = (K0 + UNIT - 1) / UNIT;
    int N1 = (K1 + UNIT - 1) / UNIT;
    int N2 = (K2 + UNIT - 1) / UNIT;
    int N01 = N0 + N1;
    int Ntot = N01 + N2;

    if (packed) {
        wect_prep_kernel<true><<<PACKB, 512, 0, stream>>>(dirs, vc, K0, P, part_off, ws);
        wect_hist_kernel<true><<<NB, BLK, 0, stream>>>(
            vc, vw, ev, ew, tv, tw, K0, K1, K2, N0, N01, Ntot, P, part_off, ws);
    } else {
        wect_prep_kernel<false><<<PACKB, 512, 0, stream>>>(dirs, vc, K0, P, part_off, ws);
        wect_hist_kernel<false><<<NB, BLK, 0, stream>>>(
            vc, vw, ev, ew, tv, tw, K0, K1, K2, N0, N01, Ntot, P, part_off, ws);
    }
    wect_reduce_kernel<<<NDIR, NH, 0, stream>>>(ws, P, part_off, out);
}